// Round 18
// baseline (159.110 us; speedup 1.0000x reference)
//
#include <hip/hip_runtime.h>
#include <hip/hip_bf16.h>
#include <math.h>

#define N_ROWS 65536
#define PSI    1024
#define DDIM   256

typedef _Float16       half8 __attribute__((ext_vector_type(8)));
typedef _Float16       half4 __attribute__((ext_vector_type(4)));
typedef float          f32x4 __attribute__((ext_vector_type(4)));

#define LOG2E 1.4426950408889634f

// Raw-instruction transcendentals (~1-2 ulp, negligible vs 3.8e-6 f16 floor).
#if __has_builtin(__builtin_amdgcn_sqrtf)
#define FSQRT(x) __builtin_amdgcn_sqrtf(x)
#else
#define FSQRT(x) sqrtf(x)
#endif
#if __has_builtin(__builtin_amdgcn_exp2f)
#define FEXP2(x) __builtin_amdgcn_exp2f(x)
#else
#define FEXP2(x) exp2f(x)
#endif
#if __has_builtin(__builtin_amdgcn_rcpf)
#define FRCP(x) __builtin_amdgcn_rcpf(x)
#else
#define FRCP(x) (1.0f / (x))
#endif

// ---------- async global->LDS, 16B per lane ----------
__device__ __forceinline__ void gload16(const void* g, void* l) {
    __builtin_amdgcn_global_load_lds(
        (const __attribute__((address_space(1))) unsigned int*)g,
        (__attribute__((address_space(3))) unsigned int*)l, 16, 0, 0);
}

// ---------- fused convert (X and S) + row norms + gsum init ----------
__global__ __launch_bounds__(256) void k_convert_all(
    const float* __restrict__ X, const float* __restrict__ S,
    _Float16* __restrict__ Xh, _Float16* __restrict__ Sh,
    float* __restrict__ x2, float* __restrict__ s2,
    float* __restrict__ gsum)
{
    const int bid = blockIdx.x;
    if (bid == 16640) {                      // re-init every call (graph replay)
        for (int i = threadIdx.x; i < PSI; i += 256) gsum[i] = 0.0f;
        return;
    }
    const float* in; _Float16* outh; float* nrm; int row;
    const int wib  = threadIdx.x >> 6;
    const int lane = threadIdx.x & 63;
    if (bid < 16384) { in = X; outh = Xh; nrm = x2; row = bid * 4 + wib; }
    else { in = S; outh = Sh; nrm = s2; row = (bid - 16384) * 4 + wib; }
    const f32x4 v = __builtin_nontemporal_load(
        (const f32x4*)&in[(size_t)row * DDIM + lane * 4]);
    float s = v[0] * v[0] + v[1] * v[1] + v[2] * v[2] + v[3] * v[3];
    #pragma unroll
    for (int o = 32; o > 0; o >>= 1) s += __shfl_down(s, o);
    if (lane == 0) nrm[row] = s;
    half4 h;
    h[0] = (_Float16)v[0]; h[1] = (_Float16)v[1];
    h[2] = (_Float16)v[2]; h[3] = (_Float16)v[3];
    *(half4*)&outh[(size_t)row * DDIM + lane * 4] = h;
}

// ---------- MFMA GEMM, 128x128 tile, BK=64, double-buffered ----------------
// Shift-free softmax: u = exp2(-sqrt(max(x2+s2-2dot,0))*w*log2e), u in
// [1e-13,1] -> no max-shift needed.
// XCD-chunked 1D grid (4096). Both-sides XOR swizzle (pre-swizzled global
// k-chunk + XOR'd ds_read).
// MODE 0: mfma(af,bf) layout (col=l15) -> cheap l4-axis shuffle reduction;
//         column sums of u accumulated atomically into gsum.
// MODE 1: SWAPPED operands mfma(bf,af): lane holds row=l15 (per fm) and 4
//         CONSECUTIVE cols (l4*4+j) -> f32x4 NT stores (16/thread vs 64
//         scalar), ~4x less store issue + addressing VALU.
template<int MODE>
__global__ __launch_bounds__(256) void k_gemm(
    const _Float16* __restrict__ Xh, const _Float16* __restrict__ Sh,
    const float* __restrict__ x2, const float* __restrict__ s2,
    const float* __restrict__ w,
    float* __restrict__ gsum, float* __restrict__ out)
{
    __shared__ _Float16 As[2][128 * 64];   // 2 x 16 KB
    __shared__ _Float16 Bs[2][128 * 64];   // 2 x 16 KB

    const int tid  = threadIdx.x;
    const int wv   = tid >> 6;
    const int wr   = wv >> 1;       // wave row half (0..1)
    const int wc   = wv & 1;        // wave col half (0..1)
    const int l15  = tid & 15;
    const int l4   = (tid & 63) >> 4;

    // XCD swizzle (nwg=4096 divisible by 8 -> bijective)
    const int fid   = blockIdx.x;
    const int wgid  = (fid & 7) * 512 + (fid >> 3);
    const int rowb  = wgid >> 3;            // 0..511
    const int row0  = rowb * 128;
    const int col0  = (wgid & 7) * 128;

    f32x4 acc[4][4];
    #pragma unroll
    for (int i = 0; i < 4; ++i)
        #pragma unroll
        for (int j = 0; j < 4; ++j) acc[i][j] = (f32x4){0.f, 0.f, 0.f, 0.f};

    // staging: lane tid covers row tid>>3 (of 32-row group), pre-swizzled
    // k-chunk ((tid&7)^((tid>>3)&7))*8 halfs. 8 lanes cover one 128B row.
    const int srow = tid >> 3;
    const int skq  = ((tid & 7) ^ (srow & 7)) * 8;
    const _Float16* gAp = Xh + (size_t)(row0 + srow) * DDIM + skq;
    const _Float16* gBp = Sh + (size_t)(col0 + srow) * DDIM + skq;

    auto stage = [&](int k0, int b) {
        _Float16* Ab = &As[b][wv * 512];
        _Float16* Bb = &Bs[b][wv * 512];
        #pragma unroll
        for (int rg = 0; rg < 4; ++rg)
            gload16(gAp + (size_t)(rg * 32) * DDIM + k0, Ab + rg * 2048);
        #pragma unroll
        for (int rg = 0; rg < 4; ++rg)
            gload16(gBp + (size_t)(rg * 32) * DDIM + k0, Bb + rg * 2048);
    };

    auto compute = [&](int b) {
        #pragma unroll
        for (int kk = 0; kk < 2; ++kk) {
            half8 af[4], bf[4];
            #pragma unroll
            for (int f = 0; f < 4; ++f) {
                const int swz = (l15 & 7) << 3;               // halfs
                const int ha = ((wr * 64 + f * 16 + l15) * 64 + kk * 32 + l4 * 8) ^ swz;
                const int hb = ((wc * 64 + f * 16 + l15) * 64 + kk * 32 + l4 * 8) ^ swz;
                af[f] = *(const half8*)&As[b][ha];
                bf[f] = *(const half8*)&Bs[b][hb];
            }
            #pragma unroll
            for (int fm = 0; fm < 4; ++fm)
                #pragma unroll
                for (int fn = 0; fn < 4; ++fn) {
                    if (MODE == 1)
                        acc[fm][fn] = __builtin_amdgcn_mfma_f32_16x16x32_f16(
                            bf[fn], af[fm], acc[fm][fn], 0, 0, 0);
                    else
                        acc[fm][fn] = __builtin_amdgcn_mfma_f32_16x16x32_f16(
                            af[fm], bf[fn], acc[fm][fn], 0, 0, 0);
                }
        }
    };

    stage(0, 0);
    __syncthreads();
    #pragma unroll
    for (int t = 0; t < 4; ++t) {           // K = 4 x 64
        if (t < 3) stage((t + 1) * 64, (t + 1) & 1);
        compute(t & 1);
        if (t < 3) __syncthreads();
    }

    if (MODE == 0) {
        // layout: col = l15 group, rows = l4*4+j
        float4 x2r[4];
        #pragma unroll
        for (int fm = 0; fm < 4; ++fm)
            x2r[fm] = *(const float4*)&x2[row0 + wr * 64 + fm * 16 + l4 * 4];
        __syncthreads();                       // As dead -> alias sum array
        float* s_sm = (float*)&As[0][0];
        if (tid < 128) s_sm[tid] = 0.0f;
        __syncthreads();
        #pragma unroll
        for (int fn = 0; fn < 4; ++fn) {
            const int cl = wc * 64 + fn * 16 + l15;
            const int c  = col0 + cl;
            const float s2c = s2[c], ww2 = w[c] * LOG2E;
            float s = 0.0f;
            #pragma unroll
            for (int fm = 0; fm < 4; ++fm) {
                const float* xr = (const float*)&x2r[fm];
                #pragma unroll
                for (int j = 0; j < 4; ++j) {
                    float d2 = xr[j] + s2c - 2.0f * acc[fm][fn][j];
                    s += FEXP2(-FSQRT(fmaxf(d2, 0.0f)) * ww2);
                }
            }
            s += __shfl_xor(s, 16);
            s += __shfl_xor(s, 32);
            if (l4 == 0) atomicAdd(&s_sm[cl], s);   // 2 waves (wr) contend
        }
        __syncthreads();
        if (tid < 128) atomicAdd(&gsum[col0 + tid], s_sm[tid]);
    } else {
        // swapped layout: row = l15 (per fm), cols = l4*4+j (4 consecutive)
        float x2s[4];
        #pragma unroll
        for (int fm = 0; fm < 4; ++fm)
            x2s[fm] = x2[row0 + wr * 64 + fm * 16 + l15];
        #pragma unroll
        for (int fn = 0; fn < 4; ++fn) {
            const int cb = col0 + wc * 64 + fn * 16 + l4 * 4;
            const f32x4 s2v = *(const f32x4*)&s2[cb];
            const f32x4 wv  = *(const f32x4*)&w[cb];
            const f32x4 gv  = *(const f32x4*)&gsum[cb];
            f32x4 w2v, rv;
            #pragma unroll
            for (int j = 0; j < 4; ++j) {
                w2v[j] = wv[j] * LOG2E;
                rv[j]  = FRCP(gv[j]);
            }
            #pragma unroll
            for (int fm = 0; fm < 4; ++fm) {
                const size_t r = (size_t)(row0 + wr * 64 + fm * 16 + l15);
                f32x4 o;
                #pragma unroll
                for (int j = 0; j < 4; ++j) {
                    float d2 = x2s[fm] + s2v[j] - 2.0f * acc[fm][fn][j];
                    o[j] = FEXP2(-FSQRT(fmaxf(d2, 0.0f)) * w2v[j]) * rv[j];
                }
                __builtin_nontemporal_store(o, (f32x4*)&out[r * PSI + cb]);
            }
        }
    }
}

extern "C" void kernel_launch(void* const* d_in, const int* in_sizes, int n_in,
                              void* d_out, int out_size, void* d_ws, size_t ws_size,
                              hipStream_t stream) {
    const float* X = (const float*)d_in[0];
    const float* S = (const float*)d_in[1];
    const float* w = (const float*)d_in[2];
    float* out = (float*)d_out;

    char* ws = (char*)d_ws;
    _Float16* Xh   = (_Float16*)(ws);                  // 33,554,432 B
    _Float16* Sh   = (_Float16*)(ws + 33554432);       //    524,288 B
    float*    x2   = (float*)   (ws + 34078720);       //    262,144 B
    float*    s2   = (float*)   (ws + 34340864);       //      4,096 B
    float*    gsum = (float*)   (ws + 34344960);       //      4,096 B

    k_convert_all<<<dim3(16641), dim3(256), 0, stream>>>(
        X, S, Xh, Sh, x2, s2, gsum);
    k_gemm<0><<<dim3(4096), dim3(256), 0, stream>>>(
        Xh, Sh, x2, s2, w, gsum, nullptr);
    k_gemm<1><<<dim3(4096), dim3(256), 0, stream>>>(
        Xh, Sh, x2, s2, w, gsum, out);
}

// Round 19
// 154.532 us; speedup vs baseline: 1.0296x; 1.0296x over previous
//
#include <hip/hip_runtime.h>
#include <hip/hip_bf16.h>
#include <math.h>

#define N_ROWS 65536
#define PSI    1024
#define DDIM   256

typedef _Float16       half8 __attribute__((ext_vector_type(8)));
typedef _Float16       half4 __attribute__((ext_vector_type(4)));
typedef float          f32x4 __attribute__((ext_vector_type(4)));

#define LOG2E 1.4426950408889634f

// Raw-instruction transcendentals (~1-2 ulp, negligible vs 3.8e-6 f16 floor).
#if __has_builtin(__builtin_amdgcn_sqrtf)
#define FSQRT(x) __builtin_amdgcn_sqrtf(x)
#else
#define FSQRT(x) sqrtf(x)
#endif
#if __has_builtin(__builtin_amdgcn_exp2f)
#define FEXP2(x) __builtin_amdgcn_exp2f(x)
#else
#define FEXP2(x) exp2f(x)
#endif
#if __has_builtin(__builtin_amdgcn_rcpf)
#define FRCP(x) __builtin_amdgcn_rcpf(x)
#else
#define FRCP(x) (1.0f / (x))
#endif

// ---------- async global->LDS, 16B per lane ----------
__device__ __forceinline__ void gload16(const void* g, void* l) {
    __builtin_amdgcn_global_load_lds(
        (const __attribute__((address_space(1))) unsigned int*)g,
        (__attribute__((address_space(3))) unsigned int*)l, 16, 0, 0);
}

// ---------- fused convert (X and S) + row norms + gsum init ----------
__global__ __launch_bounds__(256) void k_convert_all(
    const float* __restrict__ X, const float* __restrict__ S,
    _Float16* __restrict__ Xh, _Float16* __restrict__ Sh,
    float* __restrict__ x2, float* __restrict__ s2,
    float* __restrict__ gsum)
{
    const int bid = blockIdx.x;
    if (bid == 16640) {                      // re-init every call (graph replay)
        for (int i = threadIdx.x; i < PSI; i += 256) gsum[i] = 0.0f;
        return;
    }
    const float* in; _Float16* outh; float* nrm; int row;
    const int wib  = threadIdx.x >> 6;
    const int lane = threadIdx.x & 63;
    if (bid < 16384) { in = X; outh = Xh; nrm = x2; row = bid * 4 + wib; }
    else { in = S; outh = Sh; nrm = s2; row = (bid - 16384) * 4 + wib; }
    const f32x4 v = __builtin_nontemporal_load(
        (const f32x4*)&in[(size_t)row * DDIM + lane * 4]);
    float s = v[0] * v[0] + v[1] * v[1] + v[2] * v[2] + v[3] * v[3];
    #pragma unroll
    for (int o = 32; o > 0; o >>= 1) s += __shfl_down(s, o);
    if (lane == 0) nrm[row] = s;
    half4 h;
    h[0] = (_Float16)v[0]; h[1] = (_Float16)v[1];
    h[2] = (_Float16)v[2]; h[3] = (_Float16)v[3];
    *(half4*)&outh[(size_t)row * DDIM + lane * 4] = h;
}

// ---------- MFMA GEMM, 256x256 tile, BK=64, m201-style 4-phase/K-tile ------
// (R13 K-loop verbatim -- refcheck-proven.) 8 waves (2M x 4N), 128 KiB LDS.
// Per K-tile: 4 phases {ds_read subtile || stage 1 half-tile -> s_barrier ->
// setprio(1) 16 MFMA setprio(0) -> s_barrier}; ONE vmcnt(0)+barrier per
// K-tile whose 8 gloads were issued a full tile earlier.
// Swizzle both-sides: linear slot s of 128B row r holds global chunk
// s^(r&7); ds_read XORs the chunk (2-way banks = free).
// Shift-free softmax: u = exp2(-sqrt(max(x2+s2-2dot,0))*w*log2e) in
// [1e-13,1] -> no max-shift. Fast transcendentals (R17).
// MODE 0: column sums of u -> atomicAdd into gsum (no combine kernels).
// MODE 1: out = u * rcp(gsum[c])  (nontemporal, 64B-line coalesced).
template<int MODE>
__global__ __launch_bounds__(512, 2) void k_gemm(
    const _Float16* __restrict__ Xh, const _Float16* __restrict__ Sh,
    const float* __restrict__ x2, const float* __restrict__ s2,
    const float* __restrict__ w,
    float* __restrict__ gsum, float* __restrict__ out)
{
    __shared__ _Float16 As[2][2][128 * 64];   // 64 KB
    __shared__ _Float16 Bs[2][2][128 * 64];   // 64 KB

    const int tid = threadIdx.x;
    const int wv  = tid >> 6;       // 0..7
    const int wr  = wv >> 2;        // M half (128 rows)
    const int wc  = wv & 3;         // N quarter (64 cols)
    const int l15 = tid & 15;
    const int l4  = (tid & 63) >> 4;

    // XCD swizzle (nwg=1024 divisible by 8 -> bijective)
    const int fid  = blockIdx.x;
    const int wgid = (fid & 7) * 128 + (fid >> 3);
    const int rowb = wgid >> 2;          // 0..255
    const int row0 = rowb * 256;
    const int col0 = (wgid & 3) * 256;

    f32x4 acc[8][4];
    #pragma unroll
    for (int i = 0; i < 8; ++i)
        #pragma unroll
        for (int j = 0; j < 4; ++j) acc[i][j] = (f32x4){0.f, 0.f, 0.f, 0.f};

    const int grow = tid >> 3;           // 0..63
    const int gch  = (tid & 7) ^ (grow & 7);
    const _Float16* gA = Xh + (size_t)(row0 + grow) * DDIM + gch * 8;
    const _Float16* gB = Sh + (size_t)(col0 + grow) * DDIM + gch * 8;

    auto stageA = [&](int kt, int buf, int h) {
        #pragma unroll
        for (int rg = 0; rg < 2; ++rg)
            gload16(gA + (size_t)(h * 128 + rg * 64) * DDIM + kt * 64,
                    &As[buf][h][(rg * 64 + wv * 8) * 64]);
    };
    auto stageB = [&](int kt, int buf, int h) {
        #pragma unroll
        for (int rg = 0; rg < 2; ++rg)
            gload16(gB + (size_t)(h * 128 + rg * 64) * DDIM + kt * 64,
                    &Bs[buf][h][(rg * 64 + wv * 8) * 64]);
    };

    const int qa0 = l15 * 64 + ((l4)     ^ (l15 & 7)) * 8;   // kk=0
    const int qa1 = l15 * 64 + ((4 + l4) ^ (l15 & 7)) * 8;   // kk=1
    const int bof = (wc & 1) * 4096;     // 64 rows into the B half

    half8 a[4][2], blo[2][2], bhi[2][2];
    auto loadA = [&](int cur, int hsel) {     // hsel: 0 = fm0-3, 1 = fm4-7
        #pragma unroll
        for (int i = 0; i < 4; ++i) {
            a[i][0] = *(const half8*)&As[cur][wr][(hsel * 4 + i) * 1024 + qa0];
            a[i][1] = *(const half8*)&As[cur][wr][(hsel * 4 + i) * 1024 + qa1];
        }
    };
    auto loadB = [&](int cur, half8 b[2][2], int fnb) {
        #pragma unroll
        for (int jn = 0; jn < 2; ++jn) {
            b[jn][0] = *(const half8*)&Bs[cur][wc >> 1][bof + (fnb + jn) * 1024 + qa0];
            b[jn][1] = *(const half8*)&Bs[cur][wc >> 1][bof + (fnb + jn) * 1024 + qa1];
        }
    };
    auto mfmaQ = [&](half8 b[2][2], int fmb, int fnb) {
        __builtin_amdgcn_s_setprio(1);
        #pragma unroll
        for (int i = 0; i < 4; ++i)
            #pragma unroll
            for (int jn = 0; jn < 2; ++jn)
                #pragma unroll
                for (int kk = 0; kk < 2; ++kk)
                    acc[fmb + i][fnb + jn] = __builtin_amdgcn_mfma_f32_16x16x32_f16(
                        a[i][kk], b[jn][kk], acc[fmb + i][fnb + jn], 0, 0, 0);
        __builtin_amdgcn_s_setprio(0);
    };

    // ---- prologue: stage tile 0, drain, barrier ----
    stageA(0, 0, 0); stageA(0, 0, 1); stageB(0, 0, 0); stageB(0, 0, 1);
    asm volatile("s_waitcnt vmcnt(0)\ns_barrier" ::: "memory");

    #pragma unroll
    for (int t = 0; t < 4; ++t) {            // K = 4 x 64
        const int cur = t & 1, nxt = cur ^ 1;
        loadA(cur, 0); loadB(cur, blo, 0);
        if (t < 3) stageA(t + 1, nxt, 0);
        asm volatile("s_barrier" ::: "memory");
        mfmaQ(blo, 0, 0);
        asm volatile("s_barrier" ::: "memory");
        loadB(cur, bhi, 2);
        if (t < 3) stageA(t + 1, nxt, 1);
        asm volatile("s_barrier" ::: "memory");
        mfmaQ(bhi, 0, 2);
        asm volatile("s_barrier" ::: "memory");
        loadA(cur, 1);
        if (t < 3) stageB(t + 1, nxt, 0);
        asm volatile("s_barrier" ::: "memory");
        mfmaQ(bhi, 4, 2);
        asm volatile("s_barrier" ::: "memory");
        if (t < 3) stageB(t + 1, nxt, 1);
        asm volatile("s_barrier" ::: "memory");
        mfmaQ(blo, 4, 0);
        if (t < 3) asm volatile("s_waitcnt vmcnt(0)\ns_barrier" ::: "memory");
    }
    __syncthreads();

    // ---- epilogue ----
    float4 x2r[8];
    #pragma unroll
    for (int fm = 0; fm < 8; ++fm)
        x2r[fm] = *(const float4*)&x2[row0 + wr * 128 + fm * 16 + l4 * 4];

    if (MODE == 0) {
        float* s_sm = (float*)&As[0][0][0];
        if (tid < 256) s_sm[tid] = 0.0f;
        __syncthreads();
        #pragma unroll
        for (int fn = 0; fn < 4; ++fn) {
            const int cl = wc * 64 + fn * 16 + l15;
            const int c  = col0 + cl;
            const float s2c = s2[c], ww2 = w[c] * LOG2E;
            float s = 0.0f;
            #pragma unroll
            for (int fm = 0; fm < 8; ++fm) {
                const float* xr = (const float*)&x2r[fm];
                #pragma unroll
                for (int j = 0; j < 4; ++j) {
                    float d2 = xr[j] + s2c - 2.0f * acc[fm][fn][j];
                    s += FEXP2(-FSQRT(fmaxf(d2, 0.0f)) * ww2);
                }
            }
            s += __shfl_xor(s, 16);
            s += __shfl_xor(s, 32);
            if (l4 == 0) atomicAdd(&s_sm[cl], s);   // 2 waves (wr) contend
        }
        __syncthreads();
        if (tid < 256) atomicAdd(&gsum[col0 + tid], s_sm[tid]);
    } else {
        #pragma unroll
        for (int fn = 0; fn < 4; ++fn) {
            const int c = col0 + wc * 64 + fn * 16 + l15;
            const float s2c = s2[c], ww2 = w[c] * LOG2E;
            const float rsc = FRCP(gsum[c]);
            #pragma unroll
            for (int fm = 0; fm < 8; ++fm) {
                const float* xr = (const float*)&x2r[fm];
                const int rbase = row0 + wr * 128 + fm * 16 + l4 * 4;
                #pragma unroll
                for (int j = 0; j < 4; ++j) {
                    float d2 = xr[j] + s2c - 2.0f * acc[fm][fn][j];
                    float u  = FEXP2(-FSQRT(fmaxf(d2, 0.0f)) * ww2) * rsc;
                    __builtin_nontemporal_store(u, &out[(size_t)(rbase + j) * PSI + c]);
                }
            }
        }
    }
}

extern "C" void kernel_launch(void* const* d_in, const int* in_sizes, int n_in,
                              void* d_out, int out_size, void* d_ws, size_t ws_size,
                              hipStream_t stream) {
    const float* X = (const float*)d_in[0];
    const float* S = (const float*)d_in[1];
    const float* w = (const float*)d_in[2];
    float* out = (float*)d_out;

    char* ws = (char*)d_ws;
    _Float16* Xh   = (_Float16*)(ws);                  // 33,554,432 B
    _Float16* Sh   = (_Float16*)(ws + 33554432);       //    524,288 B
    float*    x2   = (float*)   (ws + 34078720);       //    262,144 B
    float*    s2   = (float*)   (ws + 34340864);       //      4,096 B
    float*    gsum = (float*)   (ws + 34344960);       //      4,096 B

    k_convert_all<<<dim3(16641), dim3(256), 0, stream>>>(
        X, S, Xh, Sh, x2, s2, gsum);
    k_gemm<0><<<dim3(1024), dim3(512), 0, stream>>>(
        Xh, Sh, x2, s2, w, gsum, nullptr);
    k_gemm<1><<<dim3(1024), dim3(512), 0, stream>>>(
        Xh, Sh, x2, s2, w, gsum, out);
}